// Round 1
// baseline (193.177 us; speedup 1.0000x reference)
//
#include <hip/hip_runtime.h>
#include <hip/hip_bf16.h>

// ---- problem constants ----
#define NB   30      // RBF basis count
#define TPTS 50      // rollout points
#define LSUB 10      // substeps per point
#define DOF  7
#define BATCH 4096
#define DIN  64
#define HID  256
#define OUTC 217     // N*DOF + DOF
#define STEPS 500    // T*L
#define DTF  0.002f  // TAU/(T*L)
#define AZ   15.0f
#define BZ   3.75f   // AZ/4
#define NELEM (BATCH*DOF)   // 28672
#define PROW 32      // padded P-table row (floats)

// ---------------------------------------------------------------------------
// Kernel 1: canonical-system + RBF table.  P[t][n] = psi_n(x_{t+1}) * x_{t+1}/sum(psi)
// Mirrors the reference's fp32 op order (iterative x update, expf).
// ---------------------------------------------------------------------------
__global__ __launch_bounds__(512) void psi_table_kernel(
    const float* __restrict__ c, const float* __restrict__ h,
    float* __restrict__ Ptab) {
  int r = threadIdx.x;          // r = 0..499 -> x after (r+1) canonical steps
  if (r >= STEPS) return;
  float x = 1.0f;
  for (int i = 0; i <= r; i++) {
    x = x + (-x) * DTF;         // x += (-A_X*x/TAU)*DT
  }
  float psi[NB];
  float s = 0.0f;
  #pragma unroll
  for (int n = 0; n < NB; n++) {
    float d = x - c[n];
    psi[n] = __expf(-h[n] * d * d) ; // use precise expf below instead
  }
  // recompute with precise expf to match jnp.exp closely
  s = 0.0f;
  #pragma unroll
  for (int n = 0; n < NB; n++) {
    float d = x - c[n];
    psi[n] = expf(-h[n] * d * d);
    s += psi[n];
  }
  float sc = x / s;
  #pragma unroll
  for (int n = 0; n < NB; n++) Ptab[r * PROW + n] = psi[n] * sc;
  Ptab[r * PROW + 30] = 0.0f;
  Ptab[r * PROW + 31] = 0.0f;
}

// ---------------------------------------------------------------------------
// Kernel 2: fused MLP:  outmat = tanh(x@W_pt + b_pt) @ W_last + b_last
// 8 rows per block, 256 threads (one output column each).
// ---------------------------------------------------------------------------
__global__ __launch_bounds__(256) void mlp_kernel(
    const float* __restrict__ x,
    const float* __restrict__ W_pt, const float* __restrict__ b_pt,
    const float* __restrict__ W_last, const float* __restrict__ b_last,
    float* __restrict__ outmat) {
  __shared__ float xs[8][DIN];
  __shared__ float fs[8][HID];
  const int row0 = blockIdx.x * 8;
  const int tid = threadIdx.x;

  for (int i = tid; i < 8 * DIN; i += 256) {
    xs[i >> 6][i & 63] = x[row0 * DIN + i];
  }
  __syncthreads();

  // stage 1: feat = tanh(x @ W_pt + b_pt); thread tid owns hidden column tid
  {
    const int j = tid;
    float acc[8];
    const float bj = b_pt[j];
    #pragma unroll
    for (int r = 0; r < 8; r++) acc[r] = bj;
    for (int k = 0; k < DIN; k++) {
      float wv = W_pt[k * HID + j];
      #pragma unroll
      for (int r = 0; r < 8; r++) acc[r] = fmaf(xs[r][k], wv, acc[r]);
    }
    #pragma unroll
    for (int r = 0; r < 8; r++) fs[r][j] = tanhf(acc[r]);
  }
  __syncthreads();

  // stage 2: outmat = feat @ W_last + b_last; thread tid owns out column tid (<217)
  if (tid < OUTC) {
    const int j = tid;
    float a2[8];
    const float bj = b_last[j];
    #pragma unroll
    for (int r = 0; r < 8; r++) a2[r] = bj;
    for (int k = 0; k < HID; k++) {
      float wv = W_last[k * OUTC + j];
      #pragma unroll
      for (int r = 0; r < 8; r++) a2[r] = fmaf(fs[r][k], wv, a2[r]);
    }
    #pragma unroll
    for (int r = 0; r < 8; r++) outmat[(row0 + r) * OUTC + j] = a2[r];
  }
}

// ---------------------------------------------------------------------------
// Kernel 3: DMP rollout.  One thread per (batch, dof) element; 500 Euler steps.
// P table staged in LDS; all-lane-uniform reads broadcast (no bank conflicts).
// ---------------------------------------------------------------------------
__global__ __launch_bounds__(64) void rollout_kernel(
    const float* __restrict__ state,
    const float* __restrict__ outmat,
    const float* __restrict__ Ptab,
    float* __restrict__ out) {
  __shared__ float P[STEPS * PROW];

  {
    const float4* src = (const float4*)Ptab;
    float4* dst = (float4*)P;
    for (int i = threadIdx.x; i < STEPS * PROW / 4; i += 64) dst[i] = src[i];
  }
  __syncthreads();

  const int e = blockIdx.x * 64 + threadIdx.x;   // 448*64 == 28672 exactly
  const int b = e / DOF;
  const int d = e - b * DOF;

  const float* orow = outmat + b * OUTC;
  float w[NB];
  #pragma unroll
  for (int n = 0; n < NB; n++) w[n] = orow[DOF + d * NB + n];

  const float goal = orow[d];
  float y = state[e];
  float z = 0.05f;               // dy0 * TAU
  const float gy0 = goal - y;

  const int outoff = b * ((TPTS + 1) * DOF) + d;
  out[outoff] = y;               // k = 0 sample

  for (int k = 1; k <= TPTS; k++) {
    #pragma unroll
    for (int i = 0; i < LSUB; i++) {
      const int t = (k - 1) * LSUB + i;
      const float* p = &P[t * PROW];
      float f = 0.0f;
      #pragma unroll
      for (int n = 0; n < NB; n++) f = fmaf(w[n], p[n], f);
      const float fx = f * gy0;
      const float dz = AZ * (BZ * (goal - y) - z) + fx;
      y = fmaf(z, DTF, y);       // y += (z/TAU)*DT   (old z)
      z = fmaf(dz, DTF, z);
    }
    out[outoff + k * DOF] = y;
  }
}

// ---------------------------------------------------------------------------
extern "C" void kernel_launch(void* const* d_in, const int* in_sizes, int n_in,
                              void* d_out, int out_size, void* d_ws, size_t ws_size,
                              hipStream_t stream) {
  const float* x      = (const float*)d_in[0];
  const float* state  = (const float*)d_in[1];
  const float* W_pt   = (const float*)d_in[2];
  const float* b_pt   = (const float*)d_in[3];
  const float* W_last = (const float*)d_in[4];
  const float* b_last = (const float*)d_in[5];
  const float* c      = (const float*)d_in[6];
  const float* h      = (const float*)d_in[7];
  float* out = (float*)d_out;

  float* Ptab   = (float*)d_ws;                         // 500*32*4 = 64000 B
  float* outmat = (float*)((char*)d_ws + 65536);        // 4096*217*4 B

  psi_table_kernel<<<1, 512, 0, stream>>>(c, h, Ptab);
  mlp_kernel<<<BATCH / 8, 256, 0, stream>>>(x, W_pt, b_pt, W_last, b_last, outmat);
  rollout_kernel<<<NELEM / 64, 64, 0, stream>>>(state, outmat, Ptab, out);
}

// Round 2
// 158.701 us; speedup vs baseline: 1.2172x; 1.2172x over previous
//
#include <hip/hip_runtime.h>
#include <hip/hip_bf16.h>

// ---- problem constants ----
#define NB    30      // RBF basis count
#define TPTS  50      // rollout points
#define LSUB  10      // substeps per point
#define DOF   7
#define BATCH 4096
#define DIN   64
#define HID   256
#define OUTC  217     // N*DOF + DOF
#define STEPS 500     // T*L
#define DTF   0.002f  // TAU/(T*L)
#define DTD   0.002
#define AZD   15.0
#define C1D   56.25   // A_Z * B_Z = 15 * 3.75
#define NELEM (BATCH*DOF)   // 28672

// ---- workspace layout (bytes) ----
#define WS_PD     0           // double[500][32]  = 128000 B
#define WS_QY     131072      // float [50][32]   = 6400 B
#define WS_QZ     139264      // float [50][32]
#define WS_CONST  147456      // float [8]
#define WS_OUTMAT 151552      // float [4096][217] = 3555328 B

// ---------------------------------------------------------------------------
// Kernel 1: canonical system + RBF table + chunk-composed affine weights.
// P[t][n] = psi_n(x_{t+1}) * x_{t+1}/sum(psi)  (fp32 math, matching reference),
// then Q_y/Q_z[k][n] = sum_i P[10k+i][n] * (M^{9-i} e2 dt)_{y,z}  in double.
// ---------------------------------------------------------------------------
__global__ __launch_bounds__(512) void setup_kernel(
    const float* __restrict__ c, const float* __restrict__ h,
    char* __restrict__ ws) {
  double* Pd  = (double*)(ws + WS_PD);
  float*  Qy  = (float*)(ws + WS_QY);
  float*  Qz  = (float*)(ws + WS_QZ);
  float*  cst = (float*)(ws + WS_CONST);
  const int r = threadIdx.x;

  if (r < STEPS) {
    // x after (r+1) canonical steps, iterated in fp32 like the reference
    float x = 1.0f;
    for (int i = 0; i <= r; i++) x = x + (-x) * DTF;
    float psi[NB];
    float s = 0.0f;
    #pragma unroll
    for (int n = 0; n < NB; n++) {
      float d = x - c[n];
      psi[n] = expf(-h[n] * d * d);
      s += psi[n];
    }
    const float sc = x / s;
    #pragma unroll
    for (int n = 0; n < NB; n++) Pd[r * 32 + n] = (double)(psi[n] * sc);
    Pd[r * 32 + 30] = 0.0;
    Pd[r * 32 + 31] = 0.0;
  }
  __syncthreads();

  if (r < TPTS) {
    // per-substep affine map: s' = M s + e2*dt*(C1*goal + fx),
    // M = [[1, dt], [-C1*dt, 1-AZ*dt]]
    const double m00 = 1.0, m01 = DTD, m10 = -C1D * DTD, m11 = 1.0 - AZD * DTD;
    double vy[10], vz[10];
    double ay = 0.0, az = 0.0;
    double uy = 0.0, uz = DTD;          // u_j = M^j e2 dt
    for (int j = 0; j < 10; j++) {
      vy[9 - j] = uy; vz[9 - j] = uz;   // v_i = M^{9-i} e2 dt
      ay += uy; az += uz;               // a = sum_j M^j e2 dt
      const double ty = m00 * uy + m01 * uz;
      const double tz = m10 * uy + m11 * uz;
      uy = ty; uz = tz;
    }
    const int k = r;
    for (int n = 0; n < 32; n++) {
      double qy = 0.0, qz = 0.0;
      for (int i = 0; i < 10; i++) {
        const double p = Pd[(10 * k + i) * 32 + n];
        qy += p * vy[i];
        qz += p * vz[i];
      }
      Qy[k * 32 + n] = (float)qy;
      Qz[k * 32 + n] = (float)qz;
    }
    if (r == 0) {
      double p00 = 1, p01 = 0, p10 = 0, p11 = 1;   // M^10
      for (int j = 0; j < 10; j++) {
        const double a2 = m00 * p00 + m01 * p10;
        const double b2 = m00 * p01 + m01 * p11;
        const double c2 = m10 * p00 + m11 * p10;
        const double d2 = m10 * p01 + m11 * p11;
        p00 = a2; p01 = b2; p10 = c2; p11 = d2;
      }
      cst[0] = (float)p00; cst[1] = (float)p01;
      cst[2] = (float)p10; cst[3] = (float)p11;
      cst[4] = (float)(ay * C1D);   // multiplies goal -> u_y
      cst[5] = (float)(az * C1D);   // multiplies goal -> u_z
    }
  }
}

// ---------------------------------------------------------------------------
// Kernel 2: fused MLP:  outmat = tanh(x@W_pt + b_pt) @ W_last + b_last
// 8 rows/block, 256 threads; float4 LDS broadcast reads, 4-wide k unroll.
// ---------------------------------------------------------------------------
__global__ __launch_bounds__(256) void mlp_kernel(
    const float* __restrict__ x,
    const float* __restrict__ W_pt, const float* __restrict__ b_pt,
    const float* __restrict__ W_last, const float* __restrict__ b_last,
    float* __restrict__ outmat) {
  __shared__ float4 xs4[8][16];                       // 8 rows x 64 cols
  __shared__ __align__(16) float fs[8][HID];          // 8 rows x 256
  const int row0 = blockIdx.x * 8;
  const int tid = threadIdx.x;

  if (tid < 128) {
    xs4[tid >> 4][tid & 15] = ((const float4*)(x + row0 * DIN))[tid];
  }
  __syncthreads();

  // stage 1: feat = tanh(x @ W_pt + b_pt); thread owns hidden column tid
  {
    const int j = tid;
    float acc[8];
    const float bj = b_pt[j];
    #pragma unroll
    for (int r = 0; r < 8; r++) acc[r] = bj;
    #pragma unroll 4
    for (int g = 0; g < 16; g++) {
      const float w0 = W_pt[(4 * g + 0) * HID + j];
      const float w1 = W_pt[(4 * g + 1) * HID + j];
      const float w2 = W_pt[(4 * g + 2) * HID + j];
      const float w3 = W_pt[(4 * g + 3) * HID + j];
      #pragma unroll
      for (int r = 0; r < 8; r++) {
        const float4 xv = xs4[r][g];
        acc[r] = fmaf(xv.x, w0, acc[r]);
        acc[r] = fmaf(xv.y, w1, acc[r]);
        acc[r] = fmaf(xv.z, w2, acc[r]);
        acc[r] = fmaf(xv.w, w3, acc[r]);
      }
    }
    #pragma unroll
    for (int r = 0; r < 8; r++) fs[r][j] = tanhf(acc[r]);
  }
  __syncthreads();

  // stage 2: outmat = feat @ W_last + b_last; thread owns out column tid
  if (tid < OUTC) {
    const int j = tid;
    float a2[8];
    const float bj = b_last[j];
    #pragma unroll
    for (int r = 0; r < 8; r++) a2[r] = bj;
    #pragma unroll 4
    for (int g = 0; g < 64; g++) {
      const float w0 = W_last[(4 * g + 0) * OUTC + j];
      const float w1 = W_last[(4 * g + 1) * OUTC + j];
      const float w2 = W_last[(4 * g + 2) * OUTC + j];
      const float w3 = W_last[(4 * g + 3) * OUTC + j];
      #pragma unroll
      for (int r = 0; r < 8; r++) {
        const float4 fv = ((const float4*)fs[r])[g];
        a2[r] = fmaf(fv.x, w0, a2[r]);
        a2[r] = fmaf(fv.y, w1, a2[r]);
        a2[r] = fmaf(fv.z, w2, a2[r]);
        a2[r] = fmaf(fv.w, w3, a2[r]);
      }
    }
    #pragma unroll
    for (int r = 0; r < 8; r++) outmat[(row0 + r) * OUTC + j] = a2[r];
  }
}

// ---------------------------------------------------------------------------
// Kernel 3: DMP rollout, chunk-composed: 50 affine steps instead of 500.
// One thread per (batch, dof) element.
// ---------------------------------------------------------------------------
__global__ __launch_bounds__(64) void rollout_kernel(
    const float* __restrict__ state,
    const float* __restrict__ outmat,
    const float* __restrict__ Qyg,
    const float* __restrict__ Qzg,
    const float* __restrict__ cst,
    float* __restrict__ out) {
  __shared__ float4 sQy4[400];   // 50 x 32 floats
  __shared__ float4 sQz4[400];
  __shared__ float sc[8];

  {
    const float4* gy = (const float4*)Qyg;
    const float4* gz = (const float4*)Qzg;
    for (int i = threadIdx.x; i < 400; i += 64) {
      sQy4[i] = gy[i];
      sQz4[i] = gz[i];
    }
    if (threadIdx.x < 8) sc[threadIdx.x] = cst[threadIdx.x];
  }
  __syncthreads();

  const float* sQy = (const float*)sQy4;
  const float* sQz = (const float*)sQz4;

  const int e = blockIdx.x * 64 + threadIdx.x;   // 448*64 == 28672 exactly
  const int b = e / DOF;
  const int d = e - b * DOF;

  const float* orow = outmat + b * OUTC;
  float w[32];
  #pragma unroll
  for (int n = 0; n < NB; n++) w[n] = orow[DOF + d * NB + n];
  w[30] = 0.0f; w[31] = 0.0f;

  const float goal = orow[d];
  float y = state[e];
  float z = 0.05f;               // dy0 * TAU
  const float gy0 = goal - y;

  const float m00 = sc[0], m01 = sc[1], m10 = sc[2], m11 = sc[3];
  const float uy = sc[4] * goal;
  const float uz = sc[5] * goal;

  const int outoff = b * ((TPTS + 1) * DOF) + d;
  out[outoff] = y;               // t = 0 sample

  for (int k = 0; k < TPTS; k++) {
    const float4* qy4 = (const float4*)(sQy + k * 32);
    const float4* qz4 = (const float4*)(sQz + k * 32);
    float fy = 0.0f, fz = 0.0f;
    #pragma unroll
    for (int q = 0; q < 8; q++) {
      const float4 a = qy4[q];
      const float4 bq = qz4[q];
      fy = fmaf(w[4 * q + 0], a.x, fy);
      fy = fmaf(w[4 * q + 1], a.y, fy);
      fy = fmaf(w[4 * q + 2], a.z, fy);
      fy = fmaf(w[4 * q + 3], a.w, fy);
      fz = fmaf(w[4 * q + 0], bq.x, fz);
      fz = fmaf(w[4 * q + 1], bq.y, fz);
      fz = fmaf(w[4 * q + 2], bq.z, fz);
      fz = fmaf(w[4 * q + 3], bq.w, fz);
    }
    const float ny = fmaf(m00, y, fmaf(m01, z, fmaf(gy0, fy, uy)));
    const float nz = fmaf(m10, y, fmaf(m11, z, fmaf(gy0, fz, uz)));
    y = ny; z = nz;
    out[outoff + (k + 1) * DOF] = y;
  }
}

// ---------------------------------------------------------------------------
extern "C" void kernel_launch(void* const* d_in, const int* in_sizes, int n_in,
                              void* d_out, int out_size, void* d_ws, size_t ws_size,
                              hipStream_t stream) {
  const float* x      = (const float*)d_in[0];
  const float* state  = (const float*)d_in[1];
  const float* W_pt   = (const float*)d_in[2];
  const float* b_pt   = (const float*)d_in[3];
  const float* W_last = (const float*)d_in[4];
  const float* b_last = (const float*)d_in[5];
  const float* c      = (const float*)d_in[6];
  const float* h      = (const float*)d_in[7];
  float* out = (float*)d_out;

  char* ws = (char*)d_ws;
  float* Qy     = (float*)(ws + WS_QY);
  float* Qz     = (float*)(ws + WS_QZ);
  float* cst    = (float*)(ws + WS_CONST);
  float* outmat = (float*)(ws + WS_OUTMAT);

  setup_kernel<<<1, 512, 0, stream>>>(c, h, ws);
  mlp_kernel<<<BATCH / 8, 256, 0, stream>>>(x, W_pt, b_pt, W_last, b_last, outmat);
  rollout_kernel<<<NELEM / 64, 64, 0, stream>>>(state, outmat, Qy, Qz, cst, out);
}

// Round 3
// 150.836 us; speedup vs baseline: 1.2807x; 1.0521x over previous
//
#include <hip/hip_runtime.h>
#include <hip/hip_bf16.h>

// ---- problem constants ----
#define NB    30      // RBF basis count
#define TPTS  50      // rollout points
#define LSUB  10      // substeps per point
#define DOF   7
#define BATCH 4096
#define DIN   64
#define HID   256
#define OUTC  217     // N*DOF + DOF
#define STEPS 500     // T*L
#define DTF   0.002f  // TAU/(T*L)
#define DTD   0.002
#define AZD   15.0
#define C1D   56.25   // A_Z * B_Z = 15 * 3.75
#define NELEM (BATCH*DOF)   // 28672

// ---- workspace layout (bytes) ----
#define WS_PD     0           // double[500][32]  = 128000 B
#define WS_QY     131072      // float [50][32]   = 6400 B
#define WS_QZ     139264      // float [50][32]
#define WS_CONST  147456      // float [8]
#define WS_WTPT   155648      // bf16 [256][64]   = 32768 B   (W_pt^T)
#define WS_WTLAST 188416      // bf16 [224][256]  = 114688 B  (W_last^T, zero-padded)
#define WS_OUTMAT 303104      // float [4096][217] = 3555328 B

typedef __attribute__((ext_vector_type(8))) short short8;
typedef __attribute__((ext_vector_type(4))) float f32x4;

__device__ __forceinline__ short f2bf(float f) {
  unsigned u = __builtin_bit_cast(unsigned, f);
  unsigned r = (u + 0x7FFFu + ((u >> 16) & 1u)) >> 16;
  return (short)r;
}

// ---------------------------------------------------------------------------
// Kernel 1: canonical system + RBF table + chunk-composed affine weights.
// ---------------------------------------------------------------------------
__global__ __launch_bounds__(512) void setup_kernel(
    const float* __restrict__ c, const float* __restrict__ h,
    char* __restrict__ ws) {
  double* Pd  = (double*)(ws + WS_PD);
  float*  Qy  = (float*)(ws + WS_QY);
  float*  Qz  = (float*)(ws + WS_QZ);
  float*  cst = (float*)(ws + WS_CONST);
  const int r = threadIdx.x;

  if (r < STEPS) {
    float x = 1.0f;
    for (int i = 0; i <= r; i++) x = x + (-x) * DTF;
    float psi[NB];
    float s = 0.0f;
    #pragma unroll
    for (int n = 0; n < NB; n++) {
      float d = x - c[n];
      psi[n] = expf(-h[n] * d * d);
      s += psi[n];
    }
    const float sc = x / s;
    #pragma unroll
    for (int n = 0; n < NB; n++) Pd[r * 32 + n] = (double)(psi[n] * sc);
    Pd[r * 32 + 30] = 0.0;
    Pd[r * 32 + 31] = 0.0;
  }
  __syncthreads();

  if (r < TPTS) {
    const double m00 = 1.0, m01 = DTD, m10 = -C1D * DTD, m11 = 1.0 - AZD * DTD;
    double vy[10], vz[10];
    double ay = 0.0, az = 0.0;
    double uy = 0.0, uz = DTD;          // u_j = M^j e2 dt
    for (int j = 0; j < 10; j++) {
      vy[9 - j] = uy; vz[9 - j] = uz;   // v_i = M^{9-i} e2 dt
      ay += uy; az += uz;
      const double ty = m00 * uy + m01 * uz;
      const double tz = m10 * uy + m11 * uz;
      uy = ty; uz = tz;
    }
    const int k = r;
    for (int n = 0; n < 32; n++) {
      double qy = 0.0, qz = 0.0;
      for (int i = 0; i < 10; i++) {
        const double p = Pd[(10 * k + i) * 32 + n];
        qy += p * vy[i];
        qz += p * vz[i];
      }
      Qy[k * 32 + n] = (float)qy;
      Qz[k * 32 + n] = (float)qz;
    }
    if (r == 0) {
      double p00 = 1, p01 = 0, p10 = 0, p11 = 1;   // M^10
      for (int j = 0; j < 10; j++) {
        const double a2 = m00 * p00 + m01 * p10;
        const double b2 = m00 * p01 + m01 * p11;
        const double c2 = m10 * p00 + m11 * p10;
        const double d2 = m10 * p01 + m11 * p11;
        p00 = a2; p01 = b2; p10 = c2; p11 = d2;
      }
      cst[0] = (float)p00; cst[1] = (float)p01;
      cst[2] = (float)p10; cst[3] = (float)p11;
      cst[4] = (float)(ay * C1D);
      cst[5] = (float)(az * C1D);
    }
  }
}

// ---------------------------------------------------------------------------
// Kernel 2: prep — cast+transpose weights to bf16 for MFMA B-fragments.
// Wt_pt[j][k] = bf16(W_pt[k][j]);  Wt_last[col][k] = bf16(W_last[k][col]) (pad 0)
// ---------------------------------------------------------------------------
__global__ __launch_bounds__(256) void prep_kernel(
    const float* __restrict__ W_pt, const float* __restrict__ W_last,
    char* __restrict__ ws) {
  short* Wt_pt   = (short*)(ws + WS_WTPT);     // [256][64]
  short* Wt_last = (short*)(ws + WS_WTLAST);   // [224][256]
  const int idx = blockIdx.x * 256 + threadIdx.x;
  if (idx < 256 * 64) {
    const int j = idx >> 6, k = idx & 63;
    Wt_pt[idx] = f2bf(W_pt[k * 256 + j]);
  }
  const int idx2 = idx - 256 * 64;
  if (idx2 >= 0 && idx2 < 224 * 256) {
    const int col = idx2 >> 8, k = idx2 & 255;
    Wt_last[idx2] = (col < OUTC) ? f2bf(W_last[k * OUTC + col]) : (short)0;
  }
}

// ---------------------------------------------------------------------------
// Kernel 3: MFMA MLP. Block = 64 batch rows x one N-half (112 cols).
// Stage A: feat = tanh(x @ W_pt + b_pt) -> bf16 LDS [64][264].
// Stage B: outmat = feat @ W_last + b_last (masked col<217).
// ---------------------------------------------------------------------------
__global__ __launch_bounds__(256) void mlp_mfma_kernel(
    const float* __restrict__ x,
    const float* __restrict__ b_pt, const float* __restrict__ b_last,
    char* __restrict__ ws) {
  const short* Wt_pt   = (const short*)(ws + WS_WTPT);
  const short* Wt_last = (const short*)(ws + WS_WTLAST);
  float* outmat = (float*)(ws + WS_OUTMAT);

  __shared__ __align__(16) short feat[64 * 264];

  const int row_blk = blockIdx.x * 64;
  const int nb = blockIdx.y;            // 0/1: N-half
  const int w  = threadIdx.x >> 6;      // wave 0..3 -> 16-row strip
  const int l  = threadIdx.x & 63;
  const int lr = l & 15;                // fragment row (A) / col (B,D)
  const int lg = l >> 4;                // k-group (8 elems each)

  // ---- stage A ----
  short8 a0, a1;
  {
    const float* xr = x + (size_t)(row_blk + 16 * w + lr) * DIN + lg * 8;
    float4 f0 = ((const float4*)xr)[0];
    float4 f1 = ((const float4*)xr)[1];
    float4 g0 = ((const float4*)(xr + 32))[0];
    float4 g1 = ((const float4*)(xr + 32))[1];
    a0[0]=f2bf(f0.x); a0[1]=f2bf(f0.y); a0[2]=f2bf(f0.z); a0[3]=f2bf(f0.w);
    a0[4]=f2bf(f1.x); a0[5]=f2bf(f1.y); a0[6]=f2bf(f1.z); a0[7]=f2bf(f1.w);
    a1[0]=f2bf(g0.x); a1[1]=f2bf(g0.y); a1[2]=f2bf(g0.z); a1[3]=f2bf(g0.w);
    a1[4]=f2bf(g1.x); a1[5]=f2bf(g1.y); a1[6]=f2bf(g1.z); a1[7]=f2bf(g1.w);
  }
  {
    f32x4 accA[16];
    #pragma unroll
    for (int ct = 0; ct < 16; ct++) accA[ct] = (f32x4){0.f, 0.f, 0.f, 0.f};
    #pragma unroll
    for (int ct = 0; ct < 16; ct++) {
      short8 b0 = *(const short8*)(Wt_pt + (16 * ct + lr) * 64 + 0  + lg * 8);
      short8 b1 = *(const short8*)(Wt_pt + (16 * ct + lr) * 64 + 32 + lg * 8);
      accA[ct] = __builtin_amdgcn_mfma_f32_16x16x32_bf16(a0, b0, accA[ct], 0, 0, 0);
      accA[ct] = __builtin_amdgcn_mfma_f32_16x16x32_bf16(a1, b1, accA[ct], 0, 0, 0);
    }
    #pragma unroll
    for (int ct = 0; ct < 16; ct++) {
      const int col = 16 * ct + lr;
      const float bias = b_pt[col];
      #pragma unroll
      for (int i = 0; i < 4; i++) {
        const int r_loc = 16 * w + lg * 4 + i;
        feat[r_loc * 264 + col] = f2bf(tanhf(accA[ct][i] + bias));
      }
    }
  }
  __syncthreads();

  // ---- stage B ----
  {
    f32x4 accB[7];
    #pragma unroll
    for (int ct = 0; ct < 7; ct++) accB[ct] = (f32x4){0.f, 0.f, 0.f, 0.f};
    const int ct_base = nb * 7;
    #pragma unroll
    for (int k0 = 0; k0 < 256; k0 += 32) {
      short8 af = *(const short8*)(feat + (16 * w + lr) * 264 + k0 + lg * 8);
      #pragma unroll
      for (int ct = 0; ct < 7; ct++) {
        short8 bf = *(const short8*)(Wt_last + (16 * (ct_base + ct) + lr) * 256 + k0 + lg * 8);
        accB[ct] = __builtin_amdgcn_mfma_f32_16x16x32_bf16(af, bf, accB[ct], 0, 0, 0);
      }
    }
    #pragma unroll
    for (int ct = 0; ct < 7; ct++) {
      const int col = 16 * (ct_base + ct) + lr;
      if (col < OUTC) {
        const float bias = b_last[col];
        #pragma unroll
        for (int i = 0; i < 4; i++) {
          const int rg = row_blk + 16 * w + lg * 4 + i;
          outmat[(size_t)rg * OUTC + col] = accB[ct][i] + bias;
        }
      }
    }
  }
}

// ---------------------------------------------------------------------------
// Kernel 4: DMP rollout, chunk-composed: 50 affine steps instead of 500.
// ---------------------------------------------------------------------------
__global__ __launch_bounds__(64) void rollout_kernel(
    const float* __restrict__ state,
    const float* __restrict__ outmat,
    const float* __restrict__ Qyg,
    const float* __restrict__ Qzg,
    const float* __restrict__ cst,
    float* __restrict__ out) {
  __shared__ float4 sQy4[400];   // 50 x 32 floats
  __shared__ float4 sQz4[400];
  __shared__ float sc[8];

  {
    const float4* gy = (const float4*)Qyg;
    const float4* gz = (const float4*)Qzg;
    for (int i = threadIdx.x; i < 400; i += 64) {
      sQy4[i] = gy[i];
      sQz4[i] = gz[i];
    }
    if (threadIdx.x < 8) sc[threadIdx.x] = cst[threadIdx.x];
  }
  __syncthreads();

  const float* sQy = (const float*)sQy4;
  const float* sQz = (const float*)sQz4;

  const int e = blockIdx.x * 64 + threadIdx.x;   // 448*64 == 28672 exactly
  const int b = e / DOF;
  const int d = e - b * DOF;

  const float* orow = outmat + (size_t)b * OUTC;
  float w[32];
  #pragma unroll
  for (int n = 0; n < NB; n++) w[n] = orow[DOF + d * NB + n];
  w[30] = 0.0f; w[31] = 0.0f;

  const float goal = orow[d];
  float y = state[e];
  float z = 0.05f;               // dy0 * TAU
  const float gy0 = goal - y;

  const float m00 = sc[0], m01 = sc[1], m10 = sc[2], m11 = sc[3];
  const float uy = sc[4] * goal;
  const float uz = sc[5] * goal;

  const int outoff = b * ((TPTS + 1) * DOF) + d;
  out[outoff] = y;               // t = 0 sample

  for (int k = 0; k < TPTS; k++) {
    const float4* qy4 = (const float4*)(sQy + k * 32);
    const float4* qz4 = (const float4*)(sQz + k * 32);
    float fy = 0.0f, fz = 0.0f;
    #pragma unroll
    for (int q = 0; q < 8; q++) {
      const float4 a = qy4[q];
      const float4 bq = qz4[q];
      fy = fmaf(w[4 * q + 0], a.x, fy);
      fy = fmaf(w[4 * q + 1], a.y, fy);
      fy = fmaf(w[4 * q + 2], a.z, fy);
      fy = fmaf(w[4 * q + 3], a.w, fy);
      fz = fmaf(w[4 * q + 0], bq.x, fz);
      fz = fmaf(w[4 * q + 1], bq.y, fz);
      fz = fmaf(w[4 * q + 2], bq.z, fz);
      fz = fmaf(w[4 * q + 3], bq.w, fz);
    }
    const float ny = fmaf(m00, y, fmaf(m01, z, fmaf(gy0, fy, uy)));
    const float nz = fmaf(m10, y, fmaf(m11, z, fmaf(gy0, fz, uz)));
    y = ny; z = nz;
    out[outoff + (k + 1) * DOF] = y;
  }
}

// ---------------------------------------------------------------------------
extern "C" void kernel_launch(void* const* d_in, const int* in_sizes, int n_in,
                              void* d_out, int out_size, void* d_ws, size_t ws_size,
                              hipStream_t stream) {
  const float* x      = (const float*)d_in[0];
  const float* state  = (const float*)d_in[1];
  const float* W_pt   = (const float*)d_in[2];
  const float* b_pt   = (const float*)d_in[3];
  const float* W_last = (const float*)d_in[4];
  const float* b_last = (const float*)d_in[5];
  const float* c      = (const float*)d_in[6];
  const float* h      = (const float*)d_in[7];
  float* out = (float*)d_out;

  char* ws = (char*)d_ws;
  float* Qy     = (float*)(ws + WS_QY);
  float* Qz     = (float*)(ws + WS_QZ);
  float* cst    = (float*)(ws + WS_CONST);
  float* outmat = (float*)(ws + WS_OUTMAT);

  prep_kernel<<<288, 256, 0, stream>>>(W_pt, W_last, ws);
  setup_kernel<<<1, 512, 0, stream>>>(c, h, ws);
  mlp_mfma_kernel<<<dim3(BATCH / 64, 2), 256, 0, stream>>>(x, b_pt, b_last, ws);
  rollout_kernel<<<NELEM / 64, 64, 0, stream>>>(state, outmat, Qy, Qz, cst, out);
}

// Round 4
// 146.198 us; speedup vs baseline: 1.3213x; 1.0317x over previous
//
#include <hip/hip_runtime.h>
#include <hip/hip_bf16.h>

// ---- problem constants ----
#define NB    30      // RBF basis count
#define TPTS  50      // rollout points
#define DOF   7
#define BATCH 4096
#define DIN   64
#define HID   256
#define OUTC  217     // N*DOF + DOF
#define STEPS 500     // T*L
#define DTF   0.002f  // TAU/(T*L)
#define DTD   0.002
#define AZD   15.0
#define C1D   56.25   // A_Z * B_Z = 15 * 3.75
#define NELEM (BATCH*DOF)   // 28672

// ---- workspace layout (bytes) ----
#define WS_PD     0           // double[500][32]  = 128000 B
#define WS_QY     131072      // float [50][32]   = 6400 B
#define WS_QZ     139264      // float [50][32]
#define WS_CONST  147456      // float [8]
#define WS_WTPT   155648      // bf16 [256][64]   = 32768 B   (W_pt^T)
#define WS_WTLAST 188416      // bf16 [224][256]  = 114688 B  (W_last^T, zero-padded)
#define WS_OUTMAT 303104      // float [4096][217] = 3555328 B

typedef __attribute__((ext_vector_type(8))) short short8;
typedef __attribute__((ext_vector_type(4))) float f32x4;

__device__ __forceinline__ short f2bf(float f) {
  unsigned u = __builtin_bit_cast(unsigned, f);
  unsigned r = (u + 0x7FFFu + ((u >> 16) & 1u)) >> 16;
  return (short)r;
}

__device__ __forceinline__ float tanh_fast(float v) {
  // 1 - 2/(e^{2v}+1); exact at +-inf, ~2^-21 rel error -> invisible after bf16
  float e = __expf(2.0f * v);
  return 1.0f - __fdividef(2.0f, e + 1.0f);
}

// ---------------------------------------------------------------------------
// Kernel A: fused setup (block 0) + weight transpose (blocks 1..288).
// Block 0: canonical system P table (fp32, reference op order), chunk-composed
// Q_y/Q_z tables + M^10 constants in double.
// Blocks 1..288: cast+transpose W_pt -> [256][64] bf16, W_last -> [224][256].
// ---------------------------------------------------------------------------
__global__ __launch_bounds__(256) void setup_prep_kernel(
    const float* __restrict__ c, const float* __restrict__ h,
    const float* __restrict__ W_pt, const float* __restrict__ W_last,
    char* __restrict__ ws) {
  const int tid = threadIdx.x;

  if (blockIdx.x == 0) {
    double* Pd  = (double*)(ws + WS_PD);
    float*  Qy  = (float*)(ws + WS_QY);
    float*  Qz  = (float*)(ws + WS_QZ);
    float*  cst = (float*)(ws + WS_CONST);

    for (int r = tid; r < STEPS; r += 256) {
      float x = 1.0f;
      for (int i = 0; i <= r; i++) x = x + (-x) * DTF;
      float psi[NB];
      float s = 0.0f;
      #pragma unroll
      for (int n = 0; n < NB; n++) {
        float d = x - c[n];
        psi[n] = expf(-h[n] * d * d);
        s += psi[n];
      }
      const float scv = x / s;
      #pragma unroll
      for (int n = 0; n < NB; n++) Pd[r * 32 + n] = (double)(psi[n] * scv);
      Pd[r * 32 + 30] = 0.0;
      Pd[r * 32 + 31] = 0.0;
    }
    __syncthreads();

    if (tid < TPTS) {
      const double m00 = 1.0, m01 = DTD, m10 = -C1D * DTD, m11 = 1.0 - AZD * DTD;
      double vy[10], vz[10];
      double ay = 0.0, az = 0.0;
      double uy = 0.0, uz = DTD;          // u_j = M^j e2 dt
      for (int j = 0; j < 10; j++) {
        vy[9 - j] = uy; vz[9 - j] = uz;   // v_i = M^{9-i} e2 dt
        ay += uy; az += uz;
        const double ty = m00 * uy + m01 * uz;
        const double tz = m10 * uy + m11 * uz;
        uy = ty; uz = tz;
      }
      const int k = tid;
      for (int n = 0; n < 32; n++) {
        double qy = 0.0, qz = 0.0;
        for (int i = 0; i < 10; i++) {
          const double p = Pd[(10 * k + i) * 32 + n];
          qy += p * vy[i];
          qz += p * vz[i];
        }
        Qy[k * 32 + n] = (float)qy;
        Qz[k * 32 + n] = (float)qz;
      }
      if (tid == 0) {
        double p00 = 1, p01 = 0, p10 = 0, p11 = 1;   // M^10
        for (int j = 0; j < 10; j++) {
          const double a2 = m00 * p00 + m01 * p10;
          const double b2 = m00 * p01 + m01 * p11;
          const double c2 = m10 * p00 + m11 * p10;
          const double d2 = m10 * p01 + m11 * p11;
          p00 = a2; p01 = b2; p10 = c2; p11 = d2;
        }
        cst[0] = (float)p00; cst[1] = (float)p01;
        cst[2] = (float)p10; cst[3] = (float)p11;
        cst[4] = (float)(ay * C1D);
        cst[5] = (float)(az * C1D);
        cst[6] = 0.0f; cst[7] = 0.0f;
      }
    }
  } else {
    short* Wt_pt   = (short*)(ws + WS_WTPT);     // [256][64]
    short* Wt_last = (short*)(ws + WS_WTLAST);   // [224][256]
    const int idx = (blockIdx.x - 1) * 256 + tid;
    if (idx < 256 * 64) {
      const int j = idx >> 6, k = idx & 63;
      Wt_pt[idx] = f2bf(W_pt[k * 256 + j]);
    }
    const int idx2 = idx - 256 * 64;
    if (idx2 >= 0 && idx2 < 224 * 256) {
      const int col = idx2 >> 8, k = idx2 & 255;
      Wt_last[idx2] = (col < OUTC) ? f2bf(W_last[k * OUTC + col]) : (short)0;
    }
  }
}

// ---------------------------------------------------------------------------
// Kernel B: MFMA MLP, single-wave blocks: 16 batch rows x one N-half (112 cols).
// 512 blocks -> 2 waves/CU across all 256 CUs.  No __syncthreads needed.
// ---------------------------------------------------------------------------
__global__ __launch_bounds__(64) void mlp_mfma_kernel(
    const float* __restrict__ x,
    const float* __restrict__ b_pt, const float* __restrict__ b_last,
    char* __restrict__ ws) {
  const short* Wt_pt   = (const short*)(ws + WS_WTPT);
  const short* Wt_last = (const short*)(ws + WS_WTLAST);
  float* outmat = (float*)(ws + WS_OUTMAT);

  __shared__ __align__(16) short feat[16 * 264];

  const int row_blk = blockIdx.x * 16;
  const int nb = blockIdx.y;            // 0/1: N-half
  const int l  = threadIdx.x;
  const int lr = l & 15;                // fragment row (A) / col (B,D)
  const int lg = l >> 4;                // k-group (8 elems each)

  // ---- stage A: feat = tanh(x @ W_pt + b_pt) ----
  short8 a0, a1;
  {
    const float* xr = x + (size_t)(row_blk + lr) * DIN + lg * 8;
    float4 f0 = ((const float4*)xr)[0];
    float4 f1 = ((const float4*)xr)[1];
    float4 g0 = ((const float4*)(xr + 32))[0];
    float4 g1 = ((const float4*)(xr + 32))[1];
    a0[0]=f2bf(f0.x); a0[1]=f2bf(f0.y); a0[2]=f2bf(f0.z); a0[3]=f2bf(f0.w);
    a0[4]=f2bf(f1.x); a0[5]=f2bf(f1.y); a0[6]=f2bf(f1.z); a0[7]=f2bf(f1.w);
    a1[0]=f2bf(g0.x); a1[1]=f2bf(g0.y); a1[2]=f2bf(g0.z); a1[3]=f2bf(g0.w);
    a1[4]=f2bf(g1.x); a1[5]=f2bf(g1.y); a1[6]=f2bf(g1.z); a1[7]=f2bf(g1.w);
  }
  {
    f32x4 accA[16];
    #pragma unroll
    for (int ct = 0; ct < 16; ct++) accA[ct] = (f32x4){0.f, 0.f, 0.f, 0.f};
    #pragma unroll
    for (int ct = 0; ct < 16; ct++) {
      short8 b0 = *(const short8*)(Wt_pt + (16 * ct + lr) * 64 + 0  + lg * 8);
      short8 b1 = *(const short8*)(Wt_pt + (16 * ct + lr) * 64 + 32 + lg * 8);
      accA[ct] = __builtin_amdgcn_mfma_f32_16x16x32_bf16(a0, b0, accA[ct], 0, 0, 0);
      accA[ct] = __builtin_amdgcn_mfma_f32_16x16x32_bf16(a1, b1, accA[ct], 0, 0, 0);
    }
    #pragma unroll
    for (int ct = 0; ct < 16; ct++) {
      const int col = 16 * ct + lr;
      const float bias = b_pt[col];
      #pragma unroll
      for (int i = 0; i < 4; i++) {
        const int r_loc = lg * 4 + i;
        feat[r_loc * 264 + col] = f2bf(tanh_fast(accA[ct][i] + bias));
      }
    }
  }
  // single wave: LDS write->read ordered by in-wave lgkmcnt; no barrier needed

  // ---- stage B: outmat = feat @ W_last + b_last ----
  {
    f32x4 accB[7];
    #pragma unroll
    for (int ct = 0; ct < 7; ct++) accB[ct] = (f32x4){0.f, 0.f, 0.f, 0.f};
    const int ct_base = nb * 7;
    #pragma unroll
    for (int k0 = 0; k0 < 256; k0 += 32) {
      short8 af = *(const short8*)(feat + lr * 264 + k0 + lg * 8);
      #pragma unroll
      for (int ct = 0; ct < 7; ct++) {
        short8 bf = *(const short8*)(Wt_last + (16 * (ct_base + ct) + lr) * 256 + k0 + lg * 8);
        accB[ct] = __builtin_amdgcn_mfma_f32_16x16x32_bf16(af, bf, accB[ct], 0, 0, 0);
      }
    }
    #pragma unroll
    for (int ct = 0; ct < 7; ct++) {
      const int col = 16 * (ct_base + ct) + lr;
      if (col < OUTC) {
        const float bias = b_last[col];
        #pragma unroll
        for (int i = 0; i < 4; i++) {
          const int rg = row_blk + lg * 4 + i;
          outmat[(size_t)rg * OUTC + col] = accB[ct][i] + bias;
        }
      }
    }
  }
}

// ---------------------------------------------------------------------------
// Kernel C: DMP rollout, chunk-composed (50 affine steps), 4 lanes per element.
// Each lane owns an 8-wide slice of the 32-wide dot; butterfly shfl_xor
// reduces; all 4 lanes redundantly carry (y,z); lane q==0 stores.
// 448 blocks x 256 threads -> 1792 waves (7/CU).
// ---------------------------------------------------------------------------
__global__ __launch_bounds__(256) void rollout_kernel(
    const float* __restrict__ state,
    const float* __restrict__ outmat,
    const float* __restrict__ Qyg,
    const float* __restrict__ Qzg,
    const float* __restrict__ cst,
    float* __restrict__ out) {
  __shared__ float4 sQy4[400];   // 50 x 32 floats
  __shared__ float4 sQz4[400];
  __shared__ float sc[8];

  const int tid = threadIdx.x;
  {
    const float4* gy = (const float4*)Qyg;
    const float4* gz = (const float4*)Qzg;
    for (int i = tid; i < 400; i += 256) {
      sQy4[i] = gy[i];
      sQz4[i] = gz[i];
    }
    if (tid < 8) sc[tid] = cst[tid];
  }
  __syncthreads();

  const float* sQy = (const float*)sQy4;
  const float* sQz = (const float*)sQz4;

  const int q  = tid & 3;        // quarter of the 32-wide dot
  const int el = tid >> 2;       // element within block (0..63)
  const int e = blockIdx.x * 64 + el;   // 448*64 == 28672
  const int b = e / DOF;
  const int d = e - b * DOF;

  const float* orow = outmat + (size_t)b * OUTC;
  float wq[8];
  #pragma unroll
  for (int j = 0; j < 8; j++) {
    const int n = 8 * q + j;
    wq[j] = (n < NB) ? orow[DOF + d * NB + n] : 0.0f;
  }

  const float goal = orow[d];
  float y = state[e];
  float z = 0.05f;               // dy0 * TAU
  const float gy0 = goal - y;

  const float m00 = sc[0], m01 = sc[1], m10 = sc[2], m11 = sc[3];
  const float uy = sc[4] * goal;
  const float uz = sc[5] * goal;

  const int outoff = b * ((TPTS + 1) * DOF) + d;
  if (q == 0) out[outoff] = y;   // t = 0 sample

  for (int k = 0; k < TPTS; k++) {
    const float4* qy4 = (const float4*)(sQy + k * 32 + 8 * q);
    const float4* qz4 = (const float4*)(sQz + k * 32 + 8 * q);
    const float4 ya = qy4[0], yb = qy4[1];
    const float4 za = qz4[0], zb = qz4[1];
    float fy = 0.0f, fz = 0.0f;
    fy = fmaf(wq[0], ya.x, fy); fy = fmaf(wq[1], ya.y, fy);
    fy = fmaf(wq[2], ya.z, fy); fy = fmaf(wq[3], ya.w, fy);
    fy = fmaf(wq[4], yb.x, fy); fy = fmaf(wq[5], yb.y, fy);
    fy = fmaf(wq[6], yb.z, fy); fy = fmaf(wq[7], yb.w, fy);
    fz = fmaf(wq[0], za.x, fz); fz = fmaf(wq[1], za.y, fz);
    fz = fmaf(wq[2], za.z, fz); fz = fmaf(wq[3], za.w, fz);
    fz = fmaf(wq[4], zb.x, fz); fz = fmaf(wq[5], zb.y, fz);
    fz = fmaf(wq[6], zb.z, fz); fz = fmaf(wq[7], zb.w, fz);
    // butterfly reduce across the 4-lane group (all lanes get the sum)
    fy += __shfl_xor(fy, 1); fy += __shfl_xor(fy, 2);
    fz += __shfl_xor(fz, 1); fz += __shfl_xor(fz, 2);
    const float ny = fmaf(m00, y, fmaf(m01, z, fmaf(gy0, fy, uy)));
    const float nz = fmaf(m10, y, fmaf(m11, z, fmaf(gy0, fz, uz)));
    y = ny; z = nz;
    if (q == 0) out[outoff + (k + 1) * DOF] = y;
  }
}

// ---------------------------------------------------------------------------
extern "C" void kernel_launch(void* const* d_in, const int* in_sizes, int n_in,
                              void* d_out, int out_size, void* d_ws, size_t ws_size,
                              hipStream_t stream) {
  const float* x      = (const float*)d_in[0];
  const float* state  = (const float*)d_in[1];
  const float* W_pt   = (const float*)d_in[2];
  const float* b_pt   = (const float*)d_in[3];
  const float* W_last = (const float*)d_in[4];
  const float* b_last = (const float*)d_in[5];
  const float* c      = (const float*)d_in[6];
  const float* h      = (const float*)d_in[7];
  float* out = (float*)d_out;

  char* ws = (char*)d_ws;
  float* Qy     = (float*)(ws + WS_QY);
  float* Qz     = (float*)(ws + WS_QZ);
  float* cst    = (float*)(ws + WS_CONST);
  float* outmat = (float*)(ws + WS_OUTMAT);

  setup_prep_kernel<<<289, 256, 0, stream>>>(c, h, W_pt, W_last, ws);
  mlp_mfma_kernel<<<dim3(BATCH / 16, 2), 64, 0, stream>>>(x, b_pt, b_last, ws);
  rollout_kernel<<<NELEM / 64, 256, 0, stream>>>(state, outmat, Qy, Qz, cst, out);
}

// Round 5
// 116.128 us; speedup vs baseline: 1.6635x; 1.2589x over previous
//
#include <hip/hip_runtime.h>
#include <hip/hip_bf16.h>

// ---- problem constants ----
#define NB    30      // RBF basis count
#define TPTS  50      // rollout points
#define DOF   7
#define BATCH 4096
#define DIN   64
#define HID   256
#define OUTC  217     // N*DOF + DOF
#define STEPS 500     // T*L
#define DTF   0.002f  // TAU/(T*L)
#define DTD   0.002
#define AZD   15.0
#define C1D   56.25   // A_Z * B_Z = 15 * 3.75
#define NELEM (BATCH*DOF)   // 28672

// ---- workspace layout (bytes) ----
#define WS_QY     131072      // float [50][32]   = 6400 B
#define WS_QZ     139264      // float [50][32]
#define WS_CONST  147456      // float [8]
#define WS_WTPT   155648      // bf16 [256][64]   = 32768 B   (W_pt^T)
#define WS_WTLAST 188416      // bf16 [224][256]  = 114688 B  (W_last^T, zero-padded)
#define WS_OUTMAT 303104      // float [4096][217] = 3555328 B

typedef __attribute__((ext_vector_type(8))) short short8;
typedef __attribute__((ext_vector_type(4))) float f32x4;

__device__ __forceinline__ short f2bf(float f) {
  unsigned u = __builtin_bit_cast(unsigned, f);
  unsigned r = (u + 0x7FFFu + ((u >> 16) & 1u)) >> 16;
  return (short)r;
}

__device__ __forceinline__ float tanh_fast(float v) {
  // 1 - 2/(e^{2v}+1); exact at +-inf, ~2^-21 rel error -> invisible after bf16
  float e = __expf(2.0f * v);
  return 1.0f - __fdividef(2.0f, e + 1.0f);
}

// ---------------------------------------------------------------------------
// Kernel A: fused setup (block 0, all-LDS) + weight transpose (blocks 1..144).
// Block 0:
//   phase 1a: thread 0 iterates the canonical system serially in fp32
//             (bit-exact to reference scan) -> xs[500] in LDS.
//   phase 1b: 500 threads compute psi rows -> P[500][32] in LDS.
//   phase 2 : 1600 (k,n) cells across 512 threads compose Q_y/Q_z in double.
// Blocks 1..144: cast+transpose W_pt -> [256][64] bf16, W_last -> [224][256].
// ---------------------------------------------------------------------------
__global__ __launch_bounds__(512) void setup_prep_kernel(
    const float* __restrict__ c, const float* __restrict__ h,
    const float* __restrict__ W_pt, const float* __restrict__ W_last,
    char* __restrict__ ws) {
  const int tid = threadIdx.x;

  if (blockIdx.x == 0) {
    __shared__ float xs[STEPS];
    __shared__ float Pl[STEPS][32];
    float* Qy  = (float*)(ws + WS_QY);
    float* Qz  = (float*)(ws + WS_QZ);
    float* cst = (float*)(ws + WS_CONST);

    if (tid == 0) {
      float x = 1.0f;
      for (int i = 0; i < STEPS; i++) {     // serial, fp32-exact (matches scan)
        x = x + (-x) * DTF;
        xs[i] = x;
      }
    }
    __syncthreads();

    if (tid < STEPS) {
      const float x = xs[tid];
      float psi[NB];
      float s = 0.0f;
      #pragma unroll
      for (int n = 0; n < NB; n++) {
        float d = x - c[n];
        psi[n] = expf(-h[n] * d * d);
        s += psi[n];
      }
      const float scv = x / s;
      #pragma unroll
      for (int n = 0; n < NB; n++) Pl[tid][n] = psi[n] * scv;
      Pl[tid][30] = 0.0f;
      Pl[tid][31] = 0.0f;
    }
    __syncthreads();

    // per-substep affine map: s' = M s + e2*dt*(C1*goal + fx),
    // M = [[1, dt], [-C1*dt, 1-AZ*dt]]
    const double m00 = 1.0, m01 = DTD, m10 = -C1D * DTD, m11 = 1.0 - AZD * DTD;
    double vy[10], vz[10];
    double ay = 0.0, az = 0.0;
    double uy = 0.0, uz = DTD;            // u_j = M^j e2 dt
    #pragma unroll
    for (int j = 0; j < 10; j++) {
      vy[9 - j] = uy; vz[9 - j] = uz;     // v_i = M^{9-i} e2 dt
      ay += uy; az += uz;
      const double ty = m00 * uy + m01 * uz;
      const double tz = m10 * uy + m11 * uz;
      uy = ty; uz = tz;
    }

    for (int cell = tid; cell < TPTS * 32; cell += 512) {
      const int k = cell >> 5, n = cell & 31;
      double qy = 0.0, qz = 0.0;
      #pragma unroll
      for (int i = 0; i < 10; i++) {
        const double p = (double)Pl[10 * k + i][n];
        qy += p * vy[i];
        qz += p * vz[i];
      }
      Qy[cell] = (float)qy;
      Qz[cell] = (float)qz;
    }

    if (tid == 0) {
      double p00 = 1, p01 = 0, p10 = 0, p11 = 1;   // M^10
      for (int j = 0; j < 10; j++) {
        const double a2 = m00 * p00 + m01 * p10;
        const double b2 = m00 * p01 + m01 * p11;
        const double c2 = m10 * p00 + m11 * p10;
        const double d2 = m10 * p01 + m11 * p11;
        p00 = a2; p01 = b2; p10 = c2; p11 = d2;
      }
      cst[0] = (float)p00; cst[1] = (float)p01;
      cst[2] = (float)p10; cst[3] = (float)p11;
      cst[4] = (float)(ay * C1D);
      cst[5] = (float)(az * C1D);
      cst[6] = 0.0f; cst[7] = 0.0f;
    }
  } else {
    short* Wt_pt   = (short*)(ws + WS_WTPT);     // [256][64]
    short* Wt_last = (short*)(ws + WS_WTLAST);   // [224][256]
    const int idx = (blockIdx.x - 1) * 512 + tid;
    if (idx < 256 * 64) {
      const int j = idx >> 6, k = idx & 63;
      Wt_pt[idx] = f2bf(W_pt[k * 256 + j]);
    }
    const int idx2 = idx - 256 * 64;
    if (idx2 >= 0 && idx2 < 224 * 256) {
      const int col = idx2 >> 8, k = idx2 & 255;
      Wt_last[idx2] = (col < OUTC) ? f2bf(W_last[k * OUTC + col]) : (short)0;
    }
  }
}

// ---------------------------------------------------------------------------
// Kernel B: MFMA MLP, single-wave blocks: 16 batch rows x one N-half (112 cols).
// 512 blocks -> 2 waves/CU across all 256 CUs.  No __syncthreads needed.
// ---------------------------------------------------------------------------
__global__ __launch_bounds__(64) void mlp_mfma_kernel(
    const float* __restrict__ x,
    const float* __restrict__ b_pt, const float* __restrict__ b_last,
    char* __restrict__ ws) {
  const short* Wt_pt   = (const short*)(ws + WS_WTPT);
  const short* Wt_last = (const short*)(ws + WS_WTLAST);
  float* outmat = (float*)(ws + WS_OUTMAT);

  __shared__ __align__(16) short feat[16 * 264];

  const int row_blk = blockIdx.x * 16;
  const int nb = blockIdx.y;            // 0/1: N-half
  const int l  = threadIdx.x;
  const int lr = l & 15;                // fragment row (A) / col (B,D)
  const int lg = l >> 4;                // k-group (8 elems each)

  // ---- stage A: feat = tanh(x @ W_pt + b_pt) ----
  short8 a0, a1;
  {
    const float* xr = x + (size_t)(row_blk + lr) * DIN + lg * 8;
    float4 f0 = ((const float4*)xr)[0];
    float4 f1 = ((const float4*)xr)[1];
    float4 g0 = ((const float4*)(xr + 32))[0];
    float4 g1 = ((const float4*)(xr + 32))[1];
    a0[0]=f2bf(f0.x); a0[1]=f2bf(f0.y); a0[2]=f2bf(f0.z); a0[3]=f2bf(f0.w);
    a0[4]=f2bf(f1.x); a0[5]=f2bf(f1.y); a0[6]=f2bf(f1.z); a0[7]=f2bf(f1.w);
    a1[0]=f2bf(g0.x); a1[1]=f2bf(g0.y); a1[2]=f2bf(g0.z); a1[3]=f2bf(g0.w);
    a1[4]=f2bf(g1.x); a1[5]=f2bf(g1.y); a1[6]=f2bf(g1.z); a1[7]=f2bf(g1.w);
  }
  {
    f32x4 accA[16];
    #pragma unroll
    for (int ct = 0; ct < 16; ct++) accA[ct] = (f32x4){0.f, 0.f, 0.f, 0.f};
    #pragma unroll
    for (int ct = 0; ct < 16; ct++) {
      short8 b0 = *(const short8*)(Wt_pt + (16 * ct + lr) * 64 + 0  + lg * 8);
      short8 b1 = *(const short8*)(Wt_pt + (16 * ct + lr) * 64 + 32 + lg * 8);
      accA[ct] = __builtin_amdgcn_mfma_f32_16x16x32_bf16(a0, b0, accA[ct], 0, 0, 0);
      accA[ct] = __builtin_amdgcn_mfma_f32_16x16x32_bf16(a1, b1, accA[ct], 0, 0, 0);
    }
    #pragma unroll
    for (int ct = 0; ct < 16; ct++) {
      const int col = 16 * ct + lr;
      const float bias = b_pt[col];
      #pragma unroll
      for (int i = 0; i < 4; i++) {
        const int r_loc = lg * 4 + i;
        feat[r_loc * 264 + col] = f2bf(tanh_fast(accA[ct][i] + bias));
      }
    }
  }
  // single wave: LDS write->read ordered by in-wave lgkmcnt; no barrier needed

  // ---- stage B: outmat = feat @ W_last + b_last ----
  {
    f32x4 accB[7];
    #pragma unroll
    for (int ct = 0; ct < 7; ct++) accB[ct] = (f32x4){0.f, 0.f, 0.f, 0.f};
    const int ct_base = nb * 7;
    #pragma unroll
    for (int k0 = 0; k0 < 256; k0 += 32) {
      short8 af = *(const short8*)(feat + lr * 264 + k0 + lg * 8);
      #pragma unroll
      for (int ct = 0; ct < 7; ct++) {
        short8 bf = *(const short8*)(Wt_last + (16 * (ct_base + ct) + lr) * 256 + k0 + lg * 8);
        accB[ct] = __builtin_amdgcn_mfma_f32_16x16x32_bf16(af, bf, accB[ct], 0, 0, 0);
      }
    }
    #pragma unroll
    for (int ct = 0; ct < 7; ct++) {
      const int col = 16 * (ct_base + ct) + lr;
      if (col < OUTC) {
        const float bias = b_last[col];
        #pragma unroll
        for (int i = 0; i < 4; i++) {
          const int rg = row_blk + lg * 4 + i;
          outmat[(size_t)rg * OUTC + col] = accB[ct][i] + bias;
        }
      }
    }
  }
}

// ---------------------------------------------------------------------------
// Kernel C: DMP rollout, chunk-composed (50 affine steps), 4 lanes per element.
// Each lane owns an 8-wide slice of the 32-wide dot; butterfly shfl_xor
// reduces; all 4 lanes redundantly carry (y,z); lane q==0 stores.
// 448 blocks x 256 threads -> 1792 waves (7/CU).
// ---------------------------------------------------------------------------
__global__ __launch_bounds__(256) void rollout_kernel(
    const float* __restrict__ state,
    const float* __restrict__ outmat,
    const float* __restrict__ Qyg,
    const float* __restrict__ Qzg,
    const float* __restrict__ cst,
    float* __restrict__ out) {
  __shared__ float4 sQy4[400];   // 50 x 32 floats
  __shared__ float4 sQz4[400];
  __shared__ float sc[8];

  const int tid = threadIdx.x;
  {
    const float4* gy = (const float4*)Qyg;
    const float4* gz = (const float4*)Qzg;
    for (int i = tid; i < 400; i += 256) {
      sQy4[i] = gy[i];
      sQz4[i] = gz[i];
    }
    if (tid < 8) sc[tid] = cst[tid];
  }
  __syncthreads();

  const float* sQy = (const float*)sQy4;
  const float* sQz = (const float*)sQz4;

  const int q  = tid & 3;        // quarter of the 32-wide dot
  const int el = tid >> 2;       // element within block (0..63)
  const int e = blockIdx.x * 64 + el;   // 448*64 == 28672
  const int b = e / DOF;
  const int d = e - b * DOF;

  const float* orow = outmat + (size_t)b * OUTC;
  float wq[8];
  #pragma unroll
  for (int j = 0; j < 8; j++) {
    const int n = 8 * q + j;
    wq[j] = (n < NB) ? orow[DOF + d * NB + n] : 0.0f;
  }

  const float goal = orow[d];
  float y = state[e];
  float z = 0.05f;               // dy0 * TAU
  const float gy0 = goal - y;

  const float m00 = sc[0], m01 = sc[1], m10 = sc[2], m11 = sc[3];
  const float uy = sc[4] * goal;
  const float uz = sc[5] * goal;

  const int outoff = b * ((TPTS + 1) * DOF) + d;
  if (q == 0) out[outoff] = y;   // t = 0 sample

  for (int k = 0; k < TPTS; k++) {
    const float4* qy4 = (const float4*)(sQy + k * 32 + 8 * q);
    const float4* qz4 = (const float4*)(sQz + k * 32 + 8 * q);
    const float4 ya = qy4[0], yb = qy4[1];
    const float4 za = qz4[0], zb = qz4[1];
    float fy = 0.0f, fz = 0.0f;
    fy = fmaf(wq[0], ya.x, fy); fy = fmaf(wq[1], ya.y, fy);
    fy = fmaf(wq[2], ya.z, fy); fy = fmaf(wq[3], ya.w, fy);
    fy = fmaf(wq[4], yb.x, fy); fy = fmaf(wq[5], yb.y, fy);
    fy = fmaf(wq[6], yb.z, fy); fy = fmaf(wq[7], yb.w, fy);
    fz = fmaf(wq[0], za.x, fz); fz = fmaf(wq[1], za.y, fz);
    fz = fmaf(wq[2], za.z, fz); fz = fmaf(wq[3], za.w, fz);
    fz = fmaf(wq[4], zb.x, fz); fz = fmaf(wq[5], zb.y, fz);
    fz = fmaf(wq[6], zb.z, fz); fz = fmaf(wq[7], zb.w, fz);
    // butterfly reduce across the 4-lane group (all lanes get the sum)
    fy += __shfl_xor(fy, 1); fy += __shfl_xor(fy, 2);
    fz += __shfl_xor(fz, 1); fz += __shfl_xor(fz, 2);
    const float ny = fmaf(m00, y, fmaf(m01, z, fmaf(gy0, fy, uy)));
    const float nz = fmaf(m10, y, fmaf(m11, z, fmaf(gy0, fz, uz)));
    y = ny; z = nz;
    if (q == 0) out[outoff + (k + 1) * DOF] = y;
  }
}

// ---------------------------------------------------------------------------
extern "C" void kernel_launch(void* const* d_in, const int* in_sizes, int n_in,
                              void* d_out, int out_size, void* d_ws, size_t ws_size,
                              hipStream_t stream) {
  const float* x      = (const float*)d_in[0];
  const float* state  = (const float*)d_in[1];
  const float* W_pt   = (const float*)d_in[2];
  const float* b_pt   = (const float*)d_in[3];
  const float* W_last = (const float*)d_in[4];
  const float* b_last = (const float*)d_in[5];
  const float* c      = (const float*)d_in[6];
  const float* h      = (const float*)d_in[7];
  float* out = (float*)d_out;

  char* ws = (char*)d_ws;
  float* Qy     = (float*)(ws + WS_QY);
  float* Qz     = (float*)(ws + WS_QZ);
  float* cst    = (float*)(ws + WS_CONST);
  float* outmat = (float*)(ws + WS_OUTMAT);

  // blocks: 1 (setup) + ceil((256*64 + 224*256)/512) = 1 + 144
  setup_prep_kernel<<<145, 512, 0, stream>>>(c, h, W_pt, W_last, ws);
  mlp_mfma_kernel<<<dim3(BATCH / 16, 2), 64, 0, stream>>>(x, b_pt, b_last, ws);
  rollout_kernel<<<NELEM / 64, 256, 0, stream>>>(state, outmat, Qy, Qz, cst, out);
}

// Round 6
// 99.879 us; speedup vs baseline: 1.9341x; 1.1627x over previous
//
#include <hip/hip_runtime.h>
#include <hip/hip_bf16.h>

// ---- problem constants ----
#define NB    30      // RBF basis count
#define TPTS  50      // rollout points
#define DOF   7
#define BATCH 4096
#define DIN   64
#define HID   256
#define OUTC  217     // N*DOF + DOF
#define STEPS 500     // T*L
#define DTF   0.002f  // TAU/(T*L)
#define DTD   0.002
#define AZD   15.0
#define C1D   56.25   // A_Z * B_Z = 15 * 3.75
#define NELEM (BATCH*DOF)   // 28672

// ---- workspace layout (bytes) ----
#define WS_QY     131072      // float [50][32]   = 6400 B
#define WS_QZ     139264      // float [50][32]
#define WS_CONST  147456      // float [8]
#define WS_WTPT   155648      // bf16 [256][64]   = 32768 B   (W_pt^T)
#define WS_WTLAST 188416      // bf16 [224][256]  = 114688 B  (W_last^T, zero-padded)

typedef __attribute__((ext_vector_type(8))) short short8;
typedef __attribute__((ext_vector_type(4))) float f32x4;

__device__ __forceinline__ short f2bf(float f) {
  unsigned u = __builtin_bit_cast(unsigned, f);
  unsigned r = (u + 0x7FFFu + ((u >> 16) & 1u)) >> 16;
  return (short)r;
}

__device__ __forceinline__ float tanh_fast(float v) {
  // 1 - 2/(e^{2v}+1); exact at +-inf, ~2^-21 rel error -> invisible after bf16
  float e = __expf(2.0f * v);
  return 1.0f - __fdividef(2.0f, e + 1.0f);
}

// ---------------------------------------------------------------------------
// Kernel A: fused setup (block 0, all-LDS) + weight transpose (blocks 1..144).
// Block 0:
//   phase 1a: thread 0 iterates the canonical system serially in fp32
//             (bit-exact to reference scan) -> xs[500] in LDS.
//   phase 1b: 500 threads compute psi rows -> P[500][32] in LDS.
//   phase 2 : 1600 (k,n) cells across 512 threads compose Q_y/Q_z in double.
// Blocks 1..144: cast+transpose W_pt -> [256][64] bf16, W_last -> [224][256].
// ---------------------------------------------------------------------------
__global__ __launch_bounds__(512) void setup_prep_kernel(
    const float* __restrict__ c, const float* __restrict__ h,
    const float* __restrict__ W_pt, const float* __restrict__ W_last,
    char* __restrict__ ws) {
  const int tid = threadIdx.x;

  if (blockIdx.x == 0) {
    __shared__ float xs[STEPS];
    __shared__ float Pl[STEPS][32];
    float* Qy  = (float*)(ws + WS_QY);
    float* Qz  = (float*)(ws + WS_QZ);
    float* cst = (float*)(ws + WS_CONST);

    if (tid == 0) {
      float x = 1.0f;
      for (int i = 0; i < STEPS; i++) {     // serial, fp32-exact (matches scan)
        x = x + (-x) * DTF;
        xs[i] = x;
      }
    }
    __syncthreads();

    if (tid < STEPS) {
      const float x = xs[tid];
      float psi[NB];
      float s = 0.0f;
      #pragma unroll
      for (int n = 0; n < NB; n++) {
        float d = x - c[n];
        psi[n] = expf(-h[n] * d * d);
        s += psi[n];
      }
      const float scv = x / s;
      #pragma unroll
      for (int n = 0; n < NB; n++) Pl[tid][n] = psi[n] * scv;
      Pl[tid][30] = 0.0f;
      Pl[tid][31] = 0.0f;
    }
    __syncthreads();

    // per-substep affine map: s' = M s + e2*dt*(C1*goal + fx),
    // M = [[1, dt], [-C1*dt, 1-AZ*dt]]
    const double m00 = 1.0, m01 = DTD, m10 = -C1D * DTD, m11 = 1.0 - AZD * DTD;
    double vy[10], vz[10];
    double ay = 0.0, az = 0.0;
    double uy = 0.0, uz = DTD;            // u_j = M^j e2 dt
    #pragma unroll
    for (int j = 0; j < 10; j++) {
      vy[9 - j] = uy; vz[9 - j] = uz;     // v_i = M^{9-i} e2 dt
      ay += uy; az += uz;
      const double ty = m00 * uy + m01 * uz;
      const double tz = m10 * uy + m11 * uz;
      uy = ty; uz = tz;
    }

    for (int cell = tid; cell < TPTS * 32; cell += 512) {
      const int k = cell >> 5, n = cell & 31;
      double qy = 0.0, qz = 0.0;
      #pragma unroll
      for (int i = 0; i < 10; i++) {
        const double p = (double)Pl[10 * k + i][n];
        qy += p * vy[i];
        qz += p * vz[i];
      }
      Qy[cell] = (float)qy;
      Qz[cell] = (float)qz;
    }

    if (tid == 0) {
      double p00 = 1, p01 = 0, p10 = 0, p11 = 1;   // M^10
      for (int j = 0; j < 10; j++) {
        const double a2 = m00 * p00 + m01 * p10;
        const double b2 = m00 * p01 + m01 * p11;
        const double c2 = m10 * p00 + m11 * p10;
        const double d2 = m10 * p01 + m11 * p11;
        p00 = a2; p01 = b2; p10 = c2; p11 = d2;
      }
      cst[0] = (float)p00; cst[1] = (float)p01;
      cst[2] = (float)p10; cst[3] = (float)p11;
      cst[4] = (float)(ay * C1D);
      cst[5] = (float)(az * C1D);
      cst[6] = 0.0f; cst[7] = 0.0f;
    }
  } else {
    short* Wt_pt   = (short*)(ws + WS_WTPT);     // [256][64]
    short* Wt_last = (short*)(ws + WS_WTLAST);   // [224][256]
    const int idx = (blockIdx.x - 1) * 512 + tid;
    if (idx < 256 * 64) {
      const int j = idx >> 6, k = idx & 63;
      Wt_pt[idx] = f2bf(W_pt[k * 256 + j]);
    }
    const int idx2 = idx - 256 * 64;
    if (idx2 >= 0 && idx2 < 224 * 256) {
      const int col = idx2 >> 8, k = idx2 & 255;
      Wt_last[idx2] = (col < OUTC) ? f2bf(W_last[k * OUTC + col]) : (short)0;
    }
  }
}

// ---------------------------------------------------------------------------
// Kernel B: fused MFMA-MLP + rollout. Block = 16 batch rows, 256 threads.
//   stage A: feat = tanh(x@W_pt+b_pt)      (4 waves x 4 ct-tiles) -> LDS bf16
//   stage B: orow = feat@W_last+b_last     (4 waves x <=4 ct-tiles) -> LDS f32
//   stage C: rollout of 112 (b,d) elements; 2 lanes/element (16-wide slices,
//            one shfl_xor); lane q==0 stores 51 samples.
// outmat never touches global memory.
// ---------------------------------------------------------------------------
__global__ __launch_bounds__(256) void mlp_rollout_kernel(
    const float* __restrict__ x,
    const float* __restrict__ state,
    const float* __restrict__ b_pt, const float* __restrict__ b_last,
    const char* __restrict__ ws,
    float* __restrict__ out) {
  const short* Wt_pt   = (const short*)(ws + WS_WTPT);
  const short* Wt_last = (const short*)(ws + WS_WTLAST);
  const float* Qyg     = (const float*)(ws + WS_QY);
  const float* Qzg     = (const float*)(ws + WS_QZ);
  const float* cstg    = (const float*)(ws + WS_CONST);

  __shared__ __align__(16) short feat[16 * 264];   // 8448 B
  __shared__ __align__(16) float orow[16][224];    // 14336 B
  __shared__ __align__(16) float sQy[TPTS * 32];   // 6400 B
  __shared__ __align__(16) float sQz[TPTS * 32];   // 6400 B
  __shared__ float sc[8];

  const int tid = threadIdx.x;
  const int w   = tid >> 6;             // wave 0..3
  const int l   = tid & 63;
  const int lr  = l & 15;               // fragment row (A) / col (B,D)
  const int lg  = l >> 4;               // k-group (8 elems each)
  const int row_blk = blockIdx.x * 16;

  // stage Q tables while stage A computes (independent)
  {
    const float4* gy = (const float4*)Qyg;
    const float4* gz = (const float4*)Qzg;
    float4* dy = (float4*)sQy;
    float4* dz = (float4*)sQz;
    for (int i = tid; i < 400; i += 256) { dy[i] = gy[i]; dz[i] = gz[i]; }
    if (tid < 8) sc[tid] = cstg[tid];
  }

  // ---- stage A: feat = tanh(x @ W_pt + b_pt); wave w owns ct = 4w..4w+3 ----
  short8 a0, a1;
  {
    const float* xr = x + (size_t)(row_blk + lr) * DIN + lg * 8;
    float4 f0 = ((const float4*)xr)[0];
    float4 f1 = ((const float4*)xr)[1];
    float4 g0 = ((const float4*)(xr + 32))[0];
    float4 g1 = ((const float4*)(xr + 32))[1];
    a0[0]=f2bf(f0.x); a0[1]=f2bf(f0.y); a0[2]=f2bf(f0.z); a0[3]=f2bf(f0.w);
    a0[4]=f2bf(f1.x); a0[5]=f2bf(f1.y); a0[6]=f2bf(f1.z); a0[7]=f2bf(f1.w);
    a1[0]=f2bf(g0.x); a1[1]=f2bf(g0.y); a1[2]=f2bf(g0.z); a1[3]=f2bf(g0.w);
    a1[4]=f2bf(g1.x); a1[5]=f2bf(g1.y); a1[6]=f2bf(g1.z); a1[7]=f2bf(g1.w);
  }
  {
    f32x4 accA[4];
    #pragma unroll
    for (int t = 0; t < 4; t++) accA[t] = (f32x4){0.f, 0.f, 0.f, 0.f};
    #pragma unroll
    for (int t = 0; t < 4; t++) {
      const int ct = 4 * w + t;
      short8 b0 = *(const short8*)(Wt_pt + (16 * ct + lr) * 64 + 0  + lg * 8);
      short8 b1 = *(const short8*)(Wt_pt + (16 * ct + lr) * 64 + 32 + lg * 8);
      accA[t] = __builtin_amdgcn_mfma_f32_16x16x32_bf16(a0, b0, accA[t], 0, 0, 0);
      accA[t] = __builtin_amdgcn_mfma_f32_16x16x32_bf16(a1, b1, accA[t], 0, 0, 0);
    }
    #pragma unroll
    for (int t = 0; t < 4; t++) {
      const int col = 16 * (4 * w + t) + lr;
      const float bias = b_pt[col];
      #pragma unroll
      for (int i = 0; i < 4; i++) {
        const int r_loc = lg * 4 + i;
        feat[r_loc * 264 + col] = f2bf(tanh_fast(accA[t][i] + bias));
      }
    }
  }
  __syncthreads();

  // ---- stage B: orow = feat @ W_last + b_last; wave w owns ct = 4w..min ----
  {
    f32x4 accB[4];
    #pragma unroll
    for (int t = 0; t < 4; t++) accB[t] = (f32x4){0.f, 0.f, 0.f, 0.f};
    const int nct = (w < 3) ? 4 : 2;        // 14 tiles: 4+4+4+2
    #pragma unroll
    for (int k0 = 0; k0 < 256; k0 += 32) {
      short8 af = *(const short8*)(feat + lr * 264 + k0 + lg * 8);
      for (int t = 0; t < 4; t++) {
        if (t < nct) {
          const int ct = 4 * w + t;
          short8 bf = *(const short8*)(Wt_last + (16 * ct + lr) * 256 + k0 + lg * 8);
          accB[t] = __builtin_amdgcn_mfma_f32_16x16x32_bf16(af, bf, accB[t], 0, 0, 0);
        }
      }
    }
    for (int t = 0; t < 4; t++) {
      if (t < nct) {
        const int col = 16 * (4 * w + t) + lr;
        const float bias = (col < OUTC) ? b_last[col] : 0.0f;
        #pragma unroll
        for (int i = 0; i < 4; i++) {
          orow[lg * 4 + i][col] = accB[t][i] + bias;
        }
      }
    }
  }
  __syncthreads();

  // ---- stage C: rollout; 2 lanes per element, 112 elements ----
  const int q  = tid & 1;          // 16-wide half of the 32-dot
  const int el = tid >> 1;         // 0..127; active < 112
  if (el < 112) {
    const int bl = el / DOF;       // batch row within block (0..15)
    const int d  = el - bl * DOF;  // dof

    float wq[16];
    #pragma unroll
    for (int j = 0; j < 16; j++) {
      const int n = 16 * q + j;
      wq[j] = (n < NB) ? orow[bl][DOF + d * NB + n] : 0.0f;
    }
    const float goal = orow[bl][d];
    const int eg = (row_blk + bl) * DOF + d;
    float y = state[eg];
    float z = 0.05f;               // dy0 * TAU
    const float gy0 = goal - y;

    const float m00 = sc[0], m01 = sc[1], m10 = sc[2], m11 = sc[3];
    const float uy = sc[4] * goal;
    const float uz = sc[5] * goal;

    const int outoff = (row_blk + bl) * ((TPTS + 1) * DOF) + d;
    if (q == 0) out[outoff] = y;   // t = 0 sample

    for (int k = 0; k < TPTS; k++) {
      const float4* qy4 = (const float4*)(sQy + k * 32 + 16 * q);
      const float4* qz4 = (const float4*)(sQz + k * 32 + 16 * q);
      float fy = 0.0f, fz = 0.0f;
      #pragma unroll
      for (int v = 0; v < 4; v++) {
        const float4 ya = qy4[v];
        const float4 za = qz4[v];
        fy = fmaf(wq[4 * v + 0], ya.x, fy);
        fy = fmaf(wq[4 * v + 1], ya.y, fy);
        fy = fmaf(wq[4 * v + 2], ya.z, fy);
        fy = fmaf(wq[4 * v + 3], ya.w, fy);
        fz = fmaf(wq[4 * v + 0], za.x, fz);
        fz = fmaf(wq[4 * v + 1], za.y, fz);
        fz = fmaf(wq[4 * v + 2], za.z, fz);
        fz = fmaf(wq[4 * v + 3], za.w, fz);
      }
      fy += __shfl_xor(fy, 1);
      fz += __shfl_xor(fz, 1);
      const float ny = fmaf(m00, y, fmaf(m01, z, fmaf(gy0, fy, uy)));
      const float nz = fmaf(m10, y, fmaf(m11, z, fmaf(gy0, fz, uz)));
      y = ny; z = nz;
      if (q == 0) out[outoff + (k + 1) * DOF] = y;
    }
  }
}

// ---------------------------------------------------------------------------
extern "C" void kernel_launch(void* const* d_in, const int* in_sizes, int n_in,
                              void* d_out, int out_size, void* d_ws, size_t ws_size,
                              hipStream_t stream) {
  const float* x      = (const float*)d_in[0];
  const float* state  = (const float*)d_in[1];
  const float* W_pt   = (const float*)d_in[2];
  const float* b_pt   = (const float*)d_in[3];
  const float* W_last = (const float*)d_in[4];
  const float* b_last = (const float*)d_in[5];
  const float* c      = (const float*)d_in[6];
  const float* h      = (const float*)d_in[7];
  float* out = (float*)d_out;

  char* ws = (char*)d_ws;

  // blocks: 1 (setup) + ceil((256*64 + 224*256)/512) = 1 + 144
  setup_prep_kernel<<<145, 512, 0, stream>>>(c, h, W_pt, W_last, ws);
  mlp_rollout_kernel<<<BATCH / 16, 256, 0, stream>>>(x, state, b_pt, b_last, ws, out);
}

// Round 7
// 92.071 us; speedup vs baseline: 2.0981x; 1.0848x over previous
//
#include <hip/hip_runtime.h>
#include <hip/hip_bf16.h>

// ---- problem constants ----
#define NB    30      // RBF basis count
#define TPTS  50      // rollout points
#define DOF   7
#define BATCH 4096
#define DIN   64
#define HID   256
#define OUTC  217     // N*DOF + DOF
#define STEPS 500     // T*L
#define DTF   0.002f  // TAU/(T*L)
#define DTD   0.002
#define AZD   15.0
#define C1D   56.25   // A_Z * B_Z = 15 * 3.75

// ---- workspace layout (bytes) ----
#define WS_WTPT   155648      // bf16 [256][64]   = 32768 B   (W_pt^T)
#define WS_WTLAST 188416      // bf16 [224][256]  = 114688 B  (W_last^T, zero-padded)

typedef __attribute__((ext_vector_type(8))) short short8;
typedef __attribute__((ext_vector_type(4))) float f32x4;

__device__ __forceinline__ short f2bf(float f) {
  unsigned u = __builtin_bit_cast(unsigned, f);
  unsigned r = (u + 0x7FFFu + ((u >> 16) & 1u)) >> 16;
  return (short)r;
}

__device__ __forceinline__ float tanh_fast(float v) {
  // 1 - 2/(e^{2v}+1); exact at +-inf, ~2^-21 rel error -> invisible after bf16
  float e = __expf(2.0f * v);
  return 1.0f - __fdividef(2.0f, e + 1.0f);
}

// ---------------------------------------------------------------------------
// Kernel 1: pure weight transpose (no serial tail).
// Wt_pt[j][k] = bf16(W_pt[k][j]); Wt_last[col][k] = bf16(W_last[k][col]) pad 0.
// 144 blocks x 512 = 73728 = 256*64 + 224*256 exactly.
// ---------------------------------------------------------------------------
__global__ __launch_bounds__(512) void prep_kernel(
    const float* __restrict__ W_pt, const float* __restrict__ W_last,
    char* __restrict__ ws) {
  short* Wt_pt   = (short*)(ws + WS_WTPT);     // [256][64]
  short* Wt_last = (short*)(ws + WS_WTLAST);   // [224][256]
  const int idx = blockIdx.x * 512 + threadIdx.x;
  if (idx < 256 * 64) {
    const int j = idx >> 6, k = idx & 63;
    Wt_pt[idx] = f2bf(W_pt[k * 256 + j]);
  } else {
    const int idx2 = idx - 256 * 64;
    const int col = idx2 >> 8, k = idx2 & 255;
    Wt_last[idx2] = (col < OUTC) ? f2bf(W_last[k * OUTC + col]) : (short)0;
  }
}

// ---------------------------------------------------------------------------
// Kernel 2: fully fused: per-block Q-table setup + MFMA MLP + rollout.
// Block = 16 batch rows, 512 threads (8 waves).
//   phase 0a: x_t = powf(1-dt, t+1), inv_t = x_t / sum(psi)      -> LDS
//   phase 0b: Q_y/Q_z[k][n] composed in double (psi recomputed)  -> LDS
//   stage A : feat = tanh(x@W_pt+b_pt)   (8 waves x 2 ct-tiles)  -> LDS bf16
//   stage B : orow = feat@W_last+b_last  (7 waves x 2 ct-tiles)  -> LDS f32
//   stage C : rollout, 4 lanes/element (8-wide slices, shfl_xor 1,2)
// ---------------------------------------------------------------------------
__global__ __launch_bounds__(512) void fused_kernel(
    const float* __restrict__ x,
    const float* __restrict__ state,
    const float* __restrict__ b_pt, const float* __restrict__ b_last,
    const float* __restrict__ cbuf, const float* __restrict__ hbuf,
    const char* __restrict__ ws,
    float* __restrict__ out) {
  const short* Wt_pt   = (const short*)(ws + WS_WTPT);
  const short* Wt_last = (const short*)(ws + WS_WTLAST);

  __shared__ __align__(16) short feat[16 * 264];   // 8448 B
  __shared__ __align__(16) float orow[16][224];    // 14336 B
  __shared__ __align__(16) float sQy[TPTS * 32];   // 6400 B
  __shared__ __align__(16) float sQz[TPTS * 32];   // 6400 B
  __shared__ float xs[STEPS];                      // 2000 B
  __shared__ float inv[STEPS];                     // 2000 B
  __shared__ float sc[8];

  const int tid = threadIdx.x;
  const int w   = tid >> 6;             // wave 0..7
  const int l   = tid & 63;
  const int lr  = l & 15;               // fragment row (A) / col (B,D)
  const int lg  = l >> 4;               // k-group (8 elems each)
  const int row_blk = blockIdx.x * 16;

  // ---- phase 0a: canonical x and 1/sum(psi) ----
  if (tid < STEPS) {
    const float xv = powf(1.0f - DTF, (float)(tid + 1));
    float s = 0.0f;
    #pragma unroll
    for (int n = 0; n < NB; n++) {
      const float d = xv - cbuf[n];
      s += expf(-hbuf[n] * d * d);
    }
    xs[tid] = xv;
    inv[tid] = xv / s;
  }
  if (tid == 0) {
    // M = [[1, dt], [-C1*dt, 1-AZ*dt]]; sc = {M^10, C1*sum_j M^j e2 dt}
    const double m00 = 1.0, m01 = DTD, m10 = -C1D * DTD, m11 = 1.0 - AZD * DTD;
    double ay = 0.0, az = 0.0;
    double uy = 0.0, uz = DTD;
    double p00 = 1, p01 = 0, p10 = 0, p11 = 1;
    for (int j = 0; j < 10; j++) {
      ay += uy; az += uz;
      const double ty = m00 * uy + m01 * uz;
      const double tz = m10 * uy + m11 * uz;
      uy = ty; uz = tz;
      const double a2 = m00 * p00 + m01 * p10;
      const double b2 = m00 * p01 + m01 * p11;
      const double c2 = m10 * p00 + m11 * p10;
      const double d2 = m10 * p01 + m11 * p11;
      p00 = a2; p01 = b2; p10 = c2; p11 = d2;
    }
    sc[0] = (float)p00; sc[1] = (float)p01;
    sc[2] = (float)p10; sc[3] = (float)p11;
    sc[4] = (float)(ay * C1D);
    sc[5] = (float)(az * C1D);
    sc[6] = 0.0f; sc[7] = 0.0f;
  }
  __syncthreads();

  // ---- phase 0b: compose Q tables (double), cells (k,n) across 512 thr ----
  {
    const double m00 = 1.0, m01 = DTD, m10 = -C1D * DTD, m11 = 1.0 - AZD * DTD;
    double vy[10], vz[10];
    double uy = 0.0, uz = DTD;            // u_j = M^j e2 dt
    #pragma unroll
    for (int j = 0; j < 10; j++) {
      vy[9 - j] = uy; vz[9 - j] = uz;     // v_i = M^{9-i} e2 dt
      const double ty = m00 * uy + m01 * uz;
      const double tz = m10 * uy + m11 * uz;
      uy = ty; uz = tz;
    }
    for (int cell = tid; cell < TPTS * 32; cell += 512) {
      const int k = cell >> 5, n = cell & 31;
      float qyf = 0.0f, qzf = 0.0f;
      if (n < NB) {
        const float cn = cbuf[n], hn = hbuf[n];
        double qy = 0.0, qz = 0.0;
        #pragma unroll
        for (int i = 0; i < 10; i++) {
          const int t = 10 * k + i;
          const float xv = xs[t];
          const float d = xv - cn;
          const float p = expf(-hn * d * d) * inv[t];
          qy += (double)p * vy[i];
          qz += (double)p * vz[i];
        }
        qyf = (float)qy; qzf = (float)qz;
      }
      sQy[cell] = qyf;
      sQz[cell] = qzf;
    }
  }

  // ---- stage A: feat = tanh(x @ W_pt + b_pt); wave w owns ct = 2w, 2w+1 ----
  short8 a0, a1;
  {
    const float* xr = x + (size_t)(row_blk + lr) * DIN + lg * 8;
    float4 f0 = ((const float4*)xr)[0];
    float4 f1 = ((const float4*)xr)[1];
    float4 g0 = ((const float4*)(xr + 32))[0];
    float4 g1 = ((const float4*)(xr + 32))[1];
    a0[0]=f2bf(f0.x); a0[1]=f2bf(f0.y); a0[2]=f2bf(f0.z); a0[3]=f2bf(f0.w);
    a0[4]=f2bf(f1.x); a0[5]=f2bf(f1.y); a0[6]=f2bf(f1.z); a0[7]=f2bf(f1.w);
    a1[0]=f2bf(g0.x); a1[1]=f2bf(g0.y); a1[2]=f2bf(g0.z); a1[3]=f2bf(g0.w);
    a1[4]=f2bf(g1.x); a1[5]=f2bf(g1.y); a1[6]=f2bf(g1.z); a1[7]=f2bf(g1.w);
  }
  {
    f32x4 accA[2];
    #pragma unroll
    for (int t = 0; t < 2; t++) accA[t] = (f32x4){0.f, 0.f, 0.f, 0.f};
    #pragma unroll
    for (int t = 0; t < 2; t++) {
      const int ct = 2 * w + t;
      short8 b0 = *(const short8*)(Wt_pt + (16 * ct + lr) * 64 + 0  + lg * 8);
      short8 b1 = *(const short8*)(Wt_pt + (16 * ct + lr) * 64 + 32 + lg * 8);
      accA[t] = __builtin_amdgcn_mfma_f32_16x16x32_bf16(a0, b0, accA[t], 0, 0, 0);
      accA[t] = __builtin_amdgcn_mfma_f32_16x16x32_bf16(a1, b1, accA[t], 0, 0, 0);
    }
    #pragma unroll
    for (int t = 0; t < 2; t++) {
      const int col = 16 * (2 * w + t) + lr;
      const float bias = b_pt[col];
      #pragma unroll
      for (int i = 0; i < 4; i++) {
        feat[(lg * 4 + i) * 264 + col] = f2bf(tanh_fast(accA[t][i] + bias));
      }
    }
  }
  __syncthreads();   // feat + Q tables ready

  // ---- stage B: orow = feat @ W_last + b_last; waves 0..6, 2 tiles each ----
  if (w < 7) {
    f32x4 accB[2];
    #pragma unroll
    for (int t = 0; t < 2; t++) accB[t] = (f32x4){0.f, 0.f, 0.f, 0.f};
    #pragma unroll
    for (int k0 = 0; k0 < 256; k0 += 32) {
      short8 af = *(const short8*)(feat + lr * 264 + k0 + lg * 8);
      #pragma unroll
      for (int t = 0; t < 2; t++) {
        const int ct = 2 * w + t;
        short8 bf = *(const short8*)(Wt_last + (16 * ct + lr) * 256 + k0 + lg * 8);
        accB[t] = __builtin_amdgcn_mfma_f32_16x16x32_bf16(af, bf, accB[t], 0, 0, 0);
      }
    }
    #pragma unroll
    for (int t = 0; t < 2; t++) {
      const int col = 16 * (2 * w + t) + lr;
      const float bias = (col < OUTC) ? b_last[col] : 0.0f;
      #pragma unroll
      for (int i = 0; i < 4; i++) {
        orow[lg * 4 + i][col] = accB[t][i] + bias;
      }
    }
  }
  __syncthreads();   // orow ready

  // ---- stage C: rollout; 4 lanes per element, 112 elements ----
  const int q  = tid & 3;          // 8-wide quarter of the 32-dot
  const int el = tid >> 2;         // 0..127; active < 112
  if (el < 112) {
    const int bl = el / DOF;       // batch row within block (0..15)
    const int d  = el - bl * DOF;  // dof

    float wq[8];
    #pragma unroll
    for (int j = 0; j < 8; j++) {
      const int n = 8 * q + j;
      wq[j] = (n < NB) ? orow[bl][DOF + d * NB + n] : 0.0f;
    }
    const float goal = orow[bl][d];
    const int eg = (row_blk + bl) * DOF + d;
    float y = state[eg];
    float z = 0.05f;               // dy0 * TAU
    const float gy0 = goal - y;

    const float m00 = sc[0], m01 = sc[1], m10 = sc[2], m11 = sc[3];
    const float uy = sc[4] * goal;
    const float uz = sc[5] * goal;

    const int outoff = eg * (TPTS + 1) - eg + eg;  // placeholder (computed below)
    const int outbase = (row_blk + bl) * ((TPTS + 1) * DOF) + d;
    (void)outoff;
    if (q == 0) out[outbase] = y;  // t = 0 sample

    for (int k = 0; k < TPTS; k++) {
      const float4* qy4 = (const float4*)(sQy + k * 32 + 8 * q);
      const float4* qz4 = (const float4*)(sQz + k * 32 + 8 * q);
      const float4 ya = qy4[0], yb = qy4[1];
      const float4 za = qz4[0], zb = qz4[1];
      float fy = 0.0f, fz = 0.0f;
      fy = fmaf(wq[0], ya.x, fy); fy = fmaf(wq[1], ya.y, fy);
      fy = fmaf(wq[2], ya.z, fy); fy = fmaf(wq[3], ya.w, fy);
      fy = fmaf(wq[4], yb.x, fy); fy = fmaf(wq[5], yb.y, fy);
      fy = fmaf(wq[6], yb.z, fy); fy = fmaf(wq[7], yb.w, fy);
      fz = fmaf(wq[0], za.x, fz); fz = fmaf(wq[1], za.y, fz);
      fz = fmaf(wq[2], za.z, fz); fz = fmaf(wq[3], za.w, fz);
      fz = fmaf(wq[4], zb.x, fz); fz = fmaf(wq[5], zb.y, fz);
      fz = fmaf(wq[6], zb.z, fz); fz = fmaf(wq[7], zb.w, fz);
      // butterfly reduce across the 4-lane group
      fy += __shfl_xor(fy, 1); fy += __shfl_xor(fy, 2);
      fz += __shfl_xor(fz, 1); fz += __shfl_xor(fz, 2);
      const float ny = fmaf(m00, y, fmaf(m01, z, fmaf(gy0, fy, uy)));
      const float nz = fmaf(m10, y, fmaf(m11, z, fmaf(gy0, fz, uz)));
      y = ny; z = nz;
      if (q == 0) out[outbase + (k + 1) * DOF] = y;
    }
  }
}

// ---------------------------------------------------------------------------
extern "C" void kernel_launch(void* const* d_in, const int* in_sizes, int n_in,
                              void* d_out, int out_size, void* d_ws, size_t ws_size,
                              hipStream_t stream) {
  const float* x      = (const float*)d_in[0];
  const float* state  = (const float*)d_in[1];
  const float* W_pt   = (const float*)d_in[2];
  const float* b_pt   = (const float*)d_in[3];
  const float* W_last = (const float*)d_in[4];
  const float* b_last = (const float*)d_in[5];
  const float* c      = (const float*)d_in[6];
  const float* h      = (const float*)d_in[7];
  float* out = (float*)d_out;

  char* ws = (char*)d_ws;

  prep_kernel<<<144, 512, 0, stream>>>(W_pt, W_last, ws);
  fused_kernel<<<BATCH / 16, 512, 0, stream>>>(x, state, b_pt, b_last, c, h, ws, out);
}